// Round 5
// baseline (181.196 us; speedup 1.0000x reference)
//
#include <hip/hip_runtime.h>
#include <hip/hip_bf16.h>

#define TLEN 4096
#define NINP 256
#define DD   64

// 1/sqrt(64) * log2(e): folded into WqT so softmax = exp2(s)
#define QSCALE 0.18033688011112042f

typedef __attribute__((ext_vector_type(8))) short bf16x8;
typedef __attribute__((ext_vector_type(4))) short bf16x4;
typedef __attribute__((ext_vector_type(4))) float f32x4;

union U8 { bf16x8 v; uint u[4]; };
union U4 { bf16x4 v; uint u[2]; };

// fp32 -> bf16 RNE (manual; v_cvt_pk_bf16_f32 is NOT RNE -> 5x absmax blowup)
__device__ inline ushort bfu(float x) {
    union { float f; uint u; } a; a.f = x;
    uint r = a.u + 0x7fffu + ((a.u >> 16) & 1u);
    return (ushort)(r >> 16);
}
__device__ inline uint pk2(float lo, float hi) {
    return (uint)bfu(lo) | ((uint)bfu(hi) << 16);
}

__device__ inline bf16x8 ld16(const ushort* p) {  // 16B-aligned global/LDS
    return *(const bf16x8*)p;
}
__device__ inline bf16x8 ld8x2(const ushort* p) { // 8B-aligned (padded LDS)
    U8 u;
    uint2 a = *(const uint2*)p;
    uint2 b = *(const uint2*)(p + 4);
    u.u[0] = a.x; u.u[1] = a.y; u.u[2] = b.x; u.u[3] = b.y;
    return u.v;
}

// ---------------------------------------------------------------------------
// prep: WT[m][d][k] = W_m[k][d] as bf16 (Wq scaled by QSCALE). LDS transpose.
// ---------------------------------------------------------------------------
__global__ __launch_bounds__(256) void prep_wt(
    const float* __restrict__ Wq, const float* __restrict__ Wk,
    const float* __restrict__ Wv, ushort* __restrict__ WT)
{
    __shared__ ushort lt[256 * 66];   // [k][d] padded
    const int t = threadIdx.x;
    const int m = blockIdx.x;
    const float* W = (m == 0) ? Wq : ((m == 1) ? Wk : Wv);
    const float scale = (m == 0) ? QSCALE : 1.0f;

    #pragma unroll
    for (int j = 0; j < 16; ++j) {
        int i4 = t + 256 * j;                 // float4 index
        float4 v = *(const float4*)&W[i4 * 4];
        int k = i4 >> 4, d = (i4 * 4) & 63;
        *(uint*)&lt[k * 66 + d]     = pk2(v.x * scale, v.y * scale);
        *(uint*)&lt[k * 66 + d + 2] = pk2(v.z * scale, v.w * scale);
    }
    __syncthreads();
    #pragma unroll
    for (int j = 0; j < 32; ++j) {            // uint (2-key) stores
        int o2 = t + 256 * j;
        int d = o2 >> 7, k = (o2 & 127) * 2;
        uint pk = (uint)lt[k * 66 + d] | ((uint)lt[(k + 1) * 66 + d] << 16);
        *(uint*)&WT[m * 16384 + d * 256 + k] = pk;
    }
}

// ---------------------------------------------------------------------------
// QKV: m-split grid (3 x rowblocks), 256 threads, 64 rows/block. Each block
// stages only its own 32KB W panel -> 43KB LDS -> 3 blocks/CU (3 waves/SIMD).
// mb=0: Q row-major, mb=1: K row-major, mb=2: VhT[d][t] via LDS repack.
// ---------------------------------------------------------------------------
__global__ __launch_bounds__(256, 3) void qkv_kernel(
    const float* __restrict__ y, const ushort* __restrict__ WT,
    ushort* __restrict__ Qh, ushort* __restrict__ Kh, ushort* __restrict__ VhT,
    const int rbn)
{
    __shared__ ushort Wl[64 * 268];   // 34,304 B (pad 268: ~2-way banks)
    __shared__ ushort tb[64 * 68];    //  8,704 B

    const int t = threadIdx.x;
    const int w = t >> 6, lane = t & 63;
    const int quad = lane >> 4, l15 = lane & 15;
    const int mb = blockIdx.x / rbn;       // 0=Q 1=K 2=V
    const int rb = blockIdx.x % rbn;
    const int rowbase = rb * 64;
    const int myrow = rowbase + w * 16 + l15;

    // ---- stage WT[mb] (32 KB): thread -> row n=t>>2, 128B segment ----
    {
        int n = t >> 2, seg = t & 3;
        const ushort* src = WT + mb * 16384 + n * 256 + seg * 64;
        ushort* dst = &Wl[n * 268 + seg * 64];
        #pragma unroll
        for (int j = 0; j < 16; ++j)
            ((uint2*)dst)[j] = ((const uint2*)src)[j];
    }

    // ---- A-fragments (overlap with staging loads) ----
    bf16x8 afrag[8];
    const float* yrow = y + (size_t)myrow * NINP;
    #pragma unroll
    for (int s = 0; s < 8; ++s) {
        float4 lo = *(const float4*)&yrow[s * 32 + quad * 8];
        float4 hi = *(const float4*)&yrow[s * 32 + quad * 8 + 4];
        U8 u;
        u.u[0] = pk2(lo.x, lo.y);
        u.u[1] = pk2(lo.z, lo.w);
        u.u[2] = pk2(hi.x, hi.y);
        u.u[3] = pk2(hi.z, hi.w);
        afrag[s] = u.v;
    }

    __syncthreads();

    f32x4 acc[4];
    #pragma unroll
    for (int nt = 0; nt < 4; ++nt) acc[nt] = f32x4{0.f, 0.f, 0.f, 0.f};

    #pragma unroll
    for (int s = 0; s < 8; ++s)
        #pragma unroll
        for (int nt = 0; nt < 4; ++nt) {
            bf16x8 bfrag = ld8x2(&Wl[(nt * 16 + l15) * 268 + s * 32 + quad * 8]);
            acc[nt] = __builtin_amdgcn_mfma_f32_16x16x32_bf16(
                afrag[s], bfrag, acc[nt], 0, 0, 0);
        }

    if (mb < 2) {
        // ---- store Q or K (row-major bf16) via LDS repack ----
        #pragma unroll
        for (int nt = 0; nt < 4; ++nt)
            #pragma unroll
            for (int r = 0; r < 4; ++r)
                tb[(w * 16 + quad * 4 + r) * 68 + nt * 16 + l15] = bfu(acc[nt][r]);
        __syncthreads();
        int row = t >> 2, seg = t & 3;
        ushort* gd = (mb == 0 ? Qh : Kh) + (size_t)(rowbase + row) * DD + seg * 16;
        const ushort* sp = &tb[row * 68 + seg * 16];
        #pragma unroll
        for (int j = 0; j < 4; ++j) ((uint2*)gd)[j] = ((const uint2*)sp)[j];
    } else {
        // ---- store VhT[d][t] ----
        #pragma unroll
        for (int nt = 0; nt < 4; ++nt) {
            int d = nt * 16 + l15;
            #pragma unroll
            for (int r = 0; r < 4; r += 2) {
                int tt = w * 16 + quad * 4 + r;
                *(uint*)&tb[d * 68 + tt] = pk2(acc[nt][r], acc[nt][r + 1]);
            }
        }
        __syncthreads();
        int d = t >> 2, seg = t & 3;
        int bb = rb >> 6;                           // batch (64 rowblocks/batch)
        int tcol = (rb & 63) * 64 + seg * 16;
        ushort* gv = VhT + ((size_t)bb * DD + d) * TLEN + tcol;
        const ushort* sp = &tb[d * 68 + seg * 16];
        #pragma unroll
        for (int j = 0; j < 4; ++j) ((uint2*)gv)[j] = ((const uint2*)sp)[j];
    }
}

// ---------------------------------------------------------------------------
// Attention: 256 blocks x 1024 threads (1 block/CU -> 16 waves/CU = 4/SIMD).
// Each block owns a COMPLETE snake pair (tile pr + tile 127-pr): wave w does
// key-seg w of tile pr, then key-seg 15-w of tile 127-pr. Per-pair chunk
// total is 65 -> cps1+cps2 = 5 for every pr -> perfectly uniform blocks.
// Combine across all 16 waves is complete (fixes R4's cross-block race).
// XCD-batch clustering: batch = (blockIdx&7)>>1 -> each XCD pair serves one
// batch -> per-XCD K+V working set 4MB = L2 (was 24MB thrash).
// S^T = K·Q^T (16x16x32). P stays IN REGISTERS: S^T's lane layout
// (key = quad*4+r, q = l15) is exactly the B-operand layout of
// mfma_f32_16x16x16_bf16, so O^T = V^T·P^T needs no LDS transpose.
// ---------------------------------------------------------------------------
__global__ __launch_bounds__(1024, 4) void attn_kernel(
    const ushort* __restrict__ Qh, const ushort* __restrict__ Kh,
    const ushort* __restrict__ VhT, float* __restrict__ out)
{
    __shared__ float Ob[16][32 * 68];   // per-wave partial O [q][d] padded
    __shared__ float lb[16][32];        // per-wave partial l

    const int t = threadIdx.x;
    const int w = t >> 6, lane = t & 63;
    const int quad = lane >> 4, l15 = lane & 15;

    // XCD-clustered decode (grid = 256, 8 XCDs, 4 batches)
    const int x = blockIdx.x & 7;
    const int b = x >> 1;
    const int pr = ((int)blockIdx.x >> 3) | ((x & 1) << 5);   // 0..63

    const ushort* Qb = Qh + (size_t)b * TLEN * DD;
    const ushort* Kb = Kh + (size_t)b * TLEN * DD;
    const ushort* Vb = VhT + (size_t)b * DD * TLEN;
    float* outb = out + (size_t)b * TLEN * DD;

    for (int half = 0; half < 2; ++half) {
        const int tile = half ? (127 - pr) : pr;
        const int seg  = half ? (15 - w) : w;
        const int qb   = tile * 32;
        const int nc   = (tile + 2) >> 1;    // 64-key chunks (masked tail)
        const int cps  = (nc + 15) >> 4;
        const int clo  = seg * cps;
        const int chi  = (nc < clo + cps) ? nc : (clo + cps);

        f32x4 oT[2][4];                      // O^T: d=nt*16+quad*4+r, q=qb+qt*16+l15
        #pragma unroll
        for (int qt = 0; qt < 2; ++qt)
            #pragma unroll
            for (int nt = 0; nt < 4; ++nt)
                oT[qt][nt] = f32x4{0.f, 0.f, 0.f, 0.f};
        float l_acc[2] = {0.f, 0.f};

        if (clo < chi) {
            // Q B-frags (fixed per tile)
            bf16x8 qf[2][2];
            #pragma unroll
            for (int qt = 0; qt < 2; ++qt)
                #pragma unroll
                for (int s = 0; s < 2; ++s)
                    qf[qt][s] = ld16(Qb + (size_t)(qb + qt * 16 + l15) * DD + s * 32 + quad * 8);

            // per-lane V^T base pointers (row = d = nt*16+l15, k-offset = quad*4)
            const ushort* vbase[4];
            #pragma unroll
            for (int nt = 0; nt < 4; ++nt)
                vbase[nt] = Vb + (size_t)(nt * 16 + l15) * TLEN + quad * 4;

            // K prefetch for first chunk
            bf16x8 kf[4][2];
            {
                int c0 = clo * 64;
                #pragma unroll
                for (int kt = 0; kt < 4; ++kt)
                    #pragma unroll
                    for (int s = 0; s < 2; ++s)
                        kf[kt][s] = ld16(Kb + (size_t)(c0 + kt * 16 + l15) * DD + s * 32 + quad * 8);
            }

            for (int ci = clo; ci < chi; ++ci) {
                const int c0 = ci * 64;

                // V^T A-frags: 16 x 8B loads (used at end of body)
                U4 vt[4][4];
                #pragma unroll
                for (int nt = 0; nt < 4; ++nt)
                    #pragma unroll
                    for (int kt = 0; kt < 4; ++kt) {
                        uint2 vv = *(const uint2*)(vbase[nt] + c0 + kt * 16);
                        vt[nt][kt].u[0] = vv.x; vt[nt][kt].u[1] = vv.y;
                    }

                // S^T = K·Q^T
                f32x4 st[2][4];
                #pragma unroll
                for (int qt = 0; qt < 2; ++qt)
                    #pragma unroll
                    for (int kt = 0; kt < 4; ++kt)
                        st[qt][kt] = f32x4{0.f, 0.f, 0.f, 0.f};
                __builtin_amdgcn_s_setprio(1);
                #pragma unroll
                for (int s = 0; s < 2; ++s)
                    #pragma unroll
                    for (int qt = 0; qt < 2; ++qt)
                        #pragma unroll
                        for (int kt = 0; kt < 4; ++kt)
                            st[qt][kt] = __builtin_amdgcn_mfma_f32_16x16x32_bf16(
                                kf[kt][s], qf[qt][s], st[qt][kt], 0, 0, 0);
                __builtin_amdgcn_s_setprio(0);

                // prefetch next chunk's K frags
                if (ci + 1 < chi) {
                    int c1 = c0 + 64;
                    #pragma unroll
                    for (int kt = 0; kt < 4; ++kt)
                        #pragma unroll
                        for (int s = 0; s < 2; ++s)
                            kf[kt][s] = ld16(Kb + (size_t)(c1 + kt * 16 + l15) * DD + s * 32 + quad * 8);
                }

                // softmax weights -> bf16 P^T frags, in-register
                U4 pa[2][4];
                if (c0 + 63 <= qb) {            // wave-uniform: fully unmasked chunk
                    #pragma unroll
                    for (int qt = 0; qt < 2; ++qt)
                        #pragma unroll
                        for (int kt = 0; kt < 4; ++kt) {
                            float p0 = exp2f(st[qt][kt][0]);
                            float p1 = exp2f(st[qt][kt][1]);
                            float p2 = exp2f(st[qt][kt][2]);
                            float p3 = exp2f(st[qt][kt][3]);
                            l_acc[qt] += (p0 + p1) + (p2 + p3);
                            pa[qt][kt].u[0] = pk2(p0, p1);
                            pa[qt][kt].u[1] = pk2(p2, p3);
                        }
                } else {                        // diagonal chunk: causal mask
                    #pragma unroll
                    for (int qt = 0; qt < 2; ++qt) {
                        const int q = qb + qt * 16 + l15;
                        #pragma unroll
                        for (int kt = 0; kt < 4; ++kt) {
                            const int kb0 = c0 + kt * 16 + quad * 4;
                            float p[4];
                            #pragma unroll
                            for (int r = 0; r < 4; ++r) {
                                float e = exp2f(st[qt][kt][r]);
                                p[r] = (kb0 + r <= q) ? e : 0.f;
                                l_acc[qt] += p[r];
                            }
                            pa[qt][kt].u[0] = pk2(p[0], p[1]);
                            pa[qt][kt].u[1] = pk2(p[2], p[3]);
                        }
                    }
                }

                // O^T += V^T · P^T   (16x16x16, K=16: B-layout == S^T lane layout)
                __builtin_amdgcn_s_setprio(1);
                #pragma unroll
                for (int qt = 0; qt < 2; ++qt)
                    #pragma unroll
                    for (int nt = 0; nt < 4; ++nt)
                        #pragma unroll
                        for (int kt = 0; kt < 4; ++kt)
                            oT[qt][nt] = __builtin_amdgcn_mfma_f32_16x16x16bf16_1k(
                                vt[nt][kt].v, pa[qt][kt].v, oT[qt][nt], 0, 0, 0);
                __builtin_amdgcn_s_setprio(0);
            }

            // reduce l across quads (keys live in quads)
            #pragma unroll
            for (int qt = 0; qt < 2; ++qt) {
                l_acc[qt] += __shfl_xor(l_acc[qt], 16, 64);
                l_acc[qt] += __shfl_xor(l_acc[qt], 32, 64);
            }
        }

        // publish partials (zeros if empty task)
        #pragma unroll
        for (int qt = 0; qt < 2; ++qt) {
            #pragma unroll
            for (int nt = 0; nt < 4; ++nt)
                #pragma unroll
                for (int r = 0; r < 4; ++r)
                    Ob[w][(qt * 16 + l15) * 68 + nt * 16 + quad * 4 + r] = oT[qt][nt][r];
            if (quad == 0) lb[w][qt * 16 + l15] = l_acc[qt];
        }
        __syncthreads();

        // in-block combine + store (complete: all 16 segs of this tile here)
        #pragma unroll
        for (int e = 0; e < 2; ++e) {
            int idx = t + 1024 * e;
            int q = idx >> 6, d = idx & 63;
            float s = 0.f, ls = 0.f;
            #pragma unroll
            for (int ww = 0; ww < 16; ++ww) {
                s += Ob[ww][q * 68 + d];
                ls += lb[ww][q];
            }
            outb[(size_t)(qb + q) * DD + d] = s * __builtin_amdgcn_rcpf(ls);
        }
        __syncthreads();
    }
}

extern "C" void kernel_launch(void* const* d_in, const int* in_sizes, int n_in,
                              void* d_out, int out_size, void* d_ws, size_t ws_size,
                              hipStream_t stream) {
    const float* y  = (const float*)d_in[0];
    const float* Wq = (const float*)d_in[1];
    const float* Wk = (const float*)d_in[2];
    const float* Wv = (const float*)d_in[3];
    float* outp = (float*)d_out;

    const int rows = in_sizes[0] / NINP;       // B*T = 16384
    const int nb = rows / TLEN;                // batches = 4
    const int rbn = rows / 64;                 // 256 row-blocks

    ushort* WT  = (ushort*)d_ws;               // 3*16384 bf16 = 96 KB
    ushort* Qh  = WT + 3 * 16384;              // rows*64 bf16 = 2 MB
    ushort* Kh  = Qh + (size_t)rows * DD;
    ushort* VhT = Kh + (size_t)rows * DD;      // [b][d][t]

    prep_wt<<<3, 256, 0, stream>>>(Wq, Wk, Wv, WT);
    qkv_kernel<<<3 * rbn, 256, 0, stream>>>(y, WT, Qh, Kh, VhT, rbn);
    attn_kernel<<<nb * 64, 1024, 0, stream>>>(Qh, Kh, VhT, outp);
}

// Round 6
// 128.755 us; speedup vs baseline: 1.4073x; 1.4073x over previous
//
#include <hip/hip_runtime.h>
#include <hip/hip_bf16.h>

#define TLEN 4096
#define NINP 256
#define DD   64

// 1/sqrt(64) * log2(e): folded into WqT so softmax = exp2(s)
#define QSCALE 0.18033688011112042f

typedef __attribute__((ext_vector_type(8))) short bf16x8;
typedef __attribute__((ext_vector_type(4))) short bf16x4;
typedef __attribute__((ext_vector_type(4))) float f32x4;

union U8 { bf16x8 v; uint u[4]; };
union U4 { bf16x4 v; uint u[2]; };

// fp32 -> bf16 RNE (manual; v_cvt_pk_bf16_f32 is NOT RNE -> 5x absmax blowup)
__device__ inline ushort bfu(float x) {
    union { float f; uint u; } a; a.f = x;
    uint r = a.u + 0x7fffu + ((a.u >> 16) & 1u);
    return (ushort)(r >> 16);
}
__device__ inline uint pk2(float lo, float hi) {
    return (uint)bfu(lo) | ((uint)bfu(hi) << 16);
}

__device__ inline bf16x8 ld16(const ushort* p) {  // 16B-aligned global/LDS
    return *(const bf16x8*)p;
}
__device__ inline bf16x8 ld8x2(const ushort* p) { // 8B-aligned (padded LDS)
    U8 u;
    uint2 a = *(const uint2*)p;
    uint2 b = *(const uint2*)(p + 4);
    u.u[0] = a.x; u.u[1] = a.y; u.u[2] = b.x; u.u[3] = b.y;
    return u.v;
}

// ---------------------------------------------------------------------------
// prep: WT[m][d][k] = W_m[k][d] as bf16 (Wq scaled by QSCALE). LDS transpose.
// ---------------------------------------------------------------------------
__global__ __launch_bounds__(256) void prep_wt(
    const float* __restrict__ Wq, const float* __restrict__ Wk,
    const float* __restrict__ Wv, ushort* __restrict__ WT)
{
    __shared__ ushort lt[256 * 66];   // [k][d] padded
    const int t = threadIdx.x;
    const int m = blockIdx.x;
    const float* W = (m == 0) ? Wq : ((m == 1) ? Wk : Wv);
    const float scale = (m == 0) ? QSCALE : 1.0f;

    #pragma unroll
    for (int j = 0; j < 16; ++j) {
        int i4 = t + 256 * j;                 // float4 index
        float4 v = *(const float4*)&W[i4 * 4];
        int k = i4 >> 4, d = (i4 * 4) & 63;
        *(uint*)&lt[k * 66 + d]     = pk2(v.x * scale, v.y * scale);
        *(uint*)&lt[k * 66 + d + 2] = pk2(v.z * scale, v.w * scale);
    }
    __syncthreads();
    #pragma unroll
    for (int j = 0; j < 32; ++j) {            // uint (2-key) stores
        int o2 = t + 256 * j;
        int d = o2 >> 7, k = (o2 & 127) * 2;
        uint pk = (uint)lt[k * 66 + d] | ((uint)lt[(k + 1) * 66 + d] << 16);
        *(uint*)&WT[m * 16384 + d * 256 + k] = pk;
    }
}

// ---------------------------------------------------------------------------
// QKV: m-split grid (3 x rowblocks), 256 threads, 64 rows/block. Each block
// stages only its own 32KB W panel -> 43KB LDS -> 3 blocks/CU (3 waves/SIMD).
// mb=0: Q row-major, mb=1: K row-major, mb=2: VhT[d][t] via LDS repack.
// ---------------------------------------------------------------------------
__global__ __launch_bounds__(256, 3) void qkv_kernel(
    const float* __restrict__ y, const ushort* __restrict__ WT,
    ushort* __restrict__ Qh, ushort* __restrict__ Kh, ushort* __restrict__ VhT,
    const int rbn)
{
    __shared__ ushort Wl[64 * 268];   // 34,304 B (pad 268: ~2-way banks)
    __shared__ ushort tb[64 * 68];    //  8,704 B

    const int t = threadIdx.x;
    const int w = t >> 6, lane = t & 63;
    const int quad = lane >> 4, l15 = lane & 15;
    const int mb = blockIdx.x / rbn;       // 0=Q 1=K 2=V
    const int rb = blockIdx.x % rbn;
    const int rowbase = rb * 64;
    const int myrow = rowbase + w * 16 + l15;

    // ---- stage WT[mb] (32 KB): thread -> row n=t>>2, 128B segment ----
    {
        int n = t >> 2, seg = t & 3;
        const ushort* src = WT + mb * 16384 + n * 256 + seg * 64;
        ushort* dst = &Wl[n * 268 + seg * 64];
        #pragma unroll
        for (int j = 0; j < 16; ++j)
            ((uint2*)dst)[j] = ((const uint2*)src)[j];
    }

    // ---- A-fragments (overlap with staging loads) ----
    bf16x8 afrag[8];
    const float* yrow = y + (size_t)myrow * NINP;
    #pragma unroll
    for (int s = 0; s < 8; ++s) {
        float4 lo = *(const float4*)&yrow[s * 32 + quad * 8];
        float4 hi = *(const float4*)&yrow[s * 32 + quad * 8 + 4];
        U8 u;
        u.u[0] = pk2(lo.x, lo.y);
        u.u[1] = pk2(lo.z, lo.w);
        u.u[2] = pk2(hi.x, hi.y);
        u.u[3] = pk2(hi.z, hi.w);
        afrag[s] = u.v;
    }

    __syncthreads();

    f32x4 acc[4];
    #pragma unroll
    for (int nt = 0; nt < 4; ++nt) acc[nt] = f32x4{0.f, 0.f, 0.f, 0.f};

    #pragma unroll
    for (int s = 0; s < 8; ++s)
        #pragma unroll
        for (int nt = 0; nt < 4; ++nt) {
            bf16x8 bfrag = ld8x2(&Wl[(nt * 16 + l15) * 268 + s * 32 + quad * 8]);
            acc[nt] = __builtin_amdgcn_mfma_f32_16x16x32_bf16(
                afrag[s], bfrag, acc[nt], 0, 0, 0);
        }

    if (mb < 2) {
        // ---- store Q or K (row-major bf16) via LDS repack ----
        #pragma unroll
        for (int nt = 0; nt < 4; ++nt)
            #pragma unroll
            for (int r = 0; r < 4; ++r)
                tb[(w * 16 + quad * 4 + r) * 68 + nt * 16 + l15] = bfu(acc[nt][r]);
        __syncthreads();
        int row = t >> 2, seg = t & 3;
        ushort* gd = (mb == 0 ? Qh : Kh) + (size_t)(rowbase + row) * DD + seg * 16;
        const ushort* sp = &tb[row * 68 + seg * 16];
        #pragma unroll
        for (int j = 0; j < 4; ++j) ((uint2*)gd)[j] = ((const uint2*)sp)[j];
    } else {
        // ---- store VhT[d][t] ----
        #pragma unroll
        for (int nt = 0; nt < 4; ++nt) {
            int d = nt * 16 + l15;
            #pragma unroll
            for (int r = 0; r < 4; r += 2) {
                int tt = w * 16 + quad * 4 + r;
                *(uint*)&tb[d * 68 + tt] = pk2(acc[nt][r], acc[nt][r + 1]);
            }
        }
        __syncthreads();
        int d = t >> 2, seg = t & 3;
        int bb = rb >> 6;                           // batch (64 rowblocks/batch)
        int tcol = (rb & 63) * 64 + seg * 16;
        ushort* gv = VhT + ((size_t)bb * DD + d) * TLEN + tcol;
        const ushort* sp = &tb[d * 68 + seg * 16];
        #pragma unroll
        for (int j = 0; j < 4; ++j) ((uint2*)gv)[j] = ((const uint2*)sp)[j];
    }
}

// ---------------------------------------------------------------------------
// Attention: 512 blocks x 512 threads, ONE complete tile per block (8-way
// key-seg split -> complete in-block combine, no cross-block race, ls>0).
// 2 blocks/CU co-resident (LDS 2x70.6=141KB<=160, VGPR 4x108=432<=512/SIMD)
// -> 16 waves/CU = 4/SIMD. launch_bounds STAYS (512,2): R5 showed (1024,4)
// caps VGPR at 64 -> 400MB scratch spill traffic. Never cap below ~110 here.
// Pair-balance: decode h=bit5(r) so CU k of an XCD gets tiles j0 and 127-j0
// (breadth-first dispatch: r=k and k+32) -> complementary durations.
// XCD-batch clustering: batch=(id&7)>>1 -> 4MB K+V per XCD = L2-resident.
// S^T = K·Q^T (16x16x32). P stays IN REGISTERS: S^T's lane layout
// (key = quad*4+r, q = l15) is exactly the B-operand layout of
// mfma_f32_16x16x16_bf16, so O^T = V^T·P^T needs no LDS transpose.
// ---------------------------------------------------------------------------
__global__ __launch_bounds__(512, 2) void attn_kernel(
    const ushort* __restrict__ Qh, const ushort* __restrict__ Kh,
    const ushort* __restrict__ VhT, float* __restrict__ out)
{
    __shared__ float Ob[8][32 * 68];    // per-wave partial O [q][d] padded
    __shared__ float lb[8][32];         // per-wave partial l

    const int t = threadIdx.x;
    const int w = t >> 6, lane = t & 63;
    const int quad = lane >> 4, l15 = lane & 15;

    // XCD-clustered, pair-balanced decode (grid = 512, 8 XCDs, 4 batches)
    const int x  = blockIdx.x & 7;
    const int b  = x >> 1;
    const int r_ = (int)blockIdx.x >> 3;          // 0..63
    const int h  = r_ >> 5;                       // pair half
    const int j0 = ((r_ & 31) << 1) | (x & 1);    // 0..63
    const int tile = h ? (127 - j0) : j0;

    const int seg = w;
    const int qb  = tile * 32;
    const int nc  = (tile + 2) >> 1;              // 64-key chunks (masked tail)
    const int cps = (nc + 7) >> 3;
    const int clo = seg * cps;
    const int chi = (nc < clo + cps) ? nc : (clo + cps);

    const ushort* Qb = Qh + (size_t)b * TLEN * DD;
    const ushort* Kb = Kh + (size_t)b * TLEN * DD;
    const ushort* Vb = VhT + (size_t)b * DD * TLEN;
    float* outb = out + (size_t)b * TLEN * DD;

    f32x4 oT[2][4];                      // O^T: d=nt*16+quad*4+r, q=qb+qt*16+l15
    #pragma unroll
    for (int qt = 0; qt < 2; ++qt)
        #pragma unroll
        for (int nt = 0; nt < 4; ++nt)
            oT[qt][nt] = f32x4{0.f, 0.f, 0.f, 0.f};
    float l_acc[2] = {0.f, 0.f};

    if (clo < chi) {
        // Q B-frags (fixed per tile)
        bf16x8 qf[2][2];
        #pragma unroll
        for (int qt = 0; qt < 2; ++qt)
            #pragma unroll
            for (int s = 0; s < 2; ++s)
                qf[qt][s] = ld16(Qb + (size_t)(qb + qt * 16 + l15) * DD + s * 32 + quad * 8);

        // per-lane V^T base pointers (row = d = nt*16+l15, k-offset = quad*4)
        const ushort* vbase[4];
        #pragma unroll
        for (int nt = 0; nt < 4; ++nt)
            vbase[nt] = Vb + (size_t)(nt * 16 + l15) * TLEN + quad * 4;

        // K prefetch for first chunk
        bf16x8 kf[4][2];
        {
            int c0 = clo * 64;
            #pragma unroll
            for (int kt = 0; kt < 4; ++kt)
                #pragma unroll
                for (int s = 0; s < 2; ++s)
                    kf[kt][s] = ld16(Kb + (size_t)(c0 + kt * 16 + l15) * DD + s * 32 + quad * 8);
        }

        for (int ci = clo; ci < chi; ++ci) {
            const int c0 = ci * 64;

            // V^T A-frags: 16 x 8B loads (used at end of body)
            U4 vt[4][4];
            #pragma unroll
            for (int nt = 0; nt < 4; ++nt)
                #pragma unroll
                for (int kt = 0; kt < 4; ++kt) {
                    uint2 vv = *(const uint2*)(vbase[nt] + c0 + kt * 16);
                    vt[nt][kt].u[0] = vv.x; vt[nt][kt].u[1] = vv.y;
                }

            // S^T = K·Q^T
            f32x4 st[2][4];
            #pragma unroll
            for (int qt = 0; qt < 2; ++qt)
                #pragma unroll
                for (int kt = 0; kt < 4; ++kt)
                    st[qt][kt] = f32x4{0.f, 0.f, 0.f, 0.f};
            __builtin_amdgcn_s_setprio(1);
            #pragma unroll
            for (int s = 0; s < 2; ++s)
                #pragma unroll
                for (int qt = 0; qt < 2; ++qt)
                    #pragma unroll
                    for (int kt = 0; kt < 4; ++kt)
                        st[qt][kt] = __builtin_amdgcn_mfma_f32_16x16x32_bf16(
                            kf[kt][s], qf[qt][s], st[qt][kt], 0, 0, 0);
            __builtin_amdgcn_s_setprio(0);

            // prefetch next chunk's K frags
            if (ci + 1 < chi) {
                int c1 = c0 + 64;
                #pragma unroll
                for (int kt = 0; kt < 4; ++kt)
                    #pragma unroll
                    for (int s = 0; s < 2; ++s)
                        kf[kt][s] = ld16(Kb + (size_t)(c1 + kt * 16 + l15) * DD + s * 32 + quad * 8);
            }

            // softmax weights -> bf16 P^T frags, in-register
            U4 pa[2][4];
            if (c0 + 63 <= qb) {            // wave-uniform: fully unmasked chunk
                #pragma unroll
                for (int qt = 0; qt < 2; ++qt)
                    #pragma unroll
                    for (int kt = 0; kt < 4; ++kt) {
                        float p0 = exp2f(st[qt][kt][0]);
                        float p1 = exp2f(st[qt][kt][1]);
                        float p2 = exp2f(st[qt][kt][2]);
                        float p3 = exp2f(st[qt][kt][3]);
                        l_acc[qt] += (p0 + p1) + (p2 + p3);
                        pa[qt][kt].u[0] = pk2(p0, p1);
                        pa[qt][kt].u[1] = pk2(p2, p3);
                    }
            } else {                        // diagonal chunk: causal mask
                #pragma unroll
                for (int qt = 0; qt < 2; ++qt) {
                    const int q = qb + qt * 16 + l15;
                    #pragma unroll
                    for (int kt = 0; kt < 4; ++kt) {
                        const int kb0 = c0 + kt * 16 + quad * 4;
                        float p[4];
                        #pragma unroll
                        for (int r = 0; r < 4; ++r) {
                            float e = exp2f(st[qt][kt][r]);
                            p[r] = (kb0 + r <= q) ? e : 0.f;
                            l_acc[qt] += p[r];
                        }
                        pa[qt][kt].u[0] = pk2(p[0], p[1]);
                        pa[qt][kt].u[1] = pk2(p[2], p[3]);
                    }
                }
            }

            // O^T += V^T · P^T   (16x16x16, K=16: B-layout == S^T lane layout)
            __builtin_amdgcn_s_setprio(1);
            #pragma unroll
            for (int qt = 0; qt < 2; ++qt)
                #pragma unroll
                for (int nt = 0; nt < 4; ++nt)
                    #pragma unroll
                    for (int kt = 0; kt < 4; ++kt)
                        oT[qt][nt] = __builtin_amdgcn_mfma_f32_16x16x16bf16_1k(
                            vt[nt][kt].v, pa[qt][kt].v, oT[qt][nt], 0, 0, 0);
            __builtin_amdgcn_s_setprio(0);
        }

        // reduce l across quads (keys live in quads)
        #pragma unroll
        for (int qt = 0; qt < 2; ++qt) {
            l_acc[qt] += __shfl_xor(l_acc[qt], 16, 64);
            l_acc[qt] += __shfl_xor(l_acc[qt], 32, 64);
        }
    }

    // publish partials (zeros if empty task)
    #pragma unroll
    for (int qt = 0; qt < 2; ++qt) {
        #pragma unroll
        for (int nt = 0; nt < 4; ++nt)
            #pragma unroll
            for (int r = 0; r < 4; ++r)
                Ob[w][(qt * 16 + l15) * 68 + nt * 16 + quad * 4 + r] = oT[qt][nt][r];
        if (quad == 0) lb[w][qt * 16 + l15] = l_acc[qt];
    }
    __syncthreads();

    // in-block combine + store (complete: all 8 segs of this tile here)
    #pragma unroll
    for (int e = 0; e < 4; ++e) {
        int idx = t + 512 * e;
        int q = idx >> 6, d = idx & 63;
        float s = 0.f, ls = 0.f;
        #pragma unroll
        for (int ww = 0; ww < 8; ++ww) {
            s += Ob[ww][q * 68 + d];
            ls += lb[ww][q];
        }
        outb[(size_t)(qb + q) * DD + d] = s * __builtin_amdgcn_rcpf(ls);
    }
}

extern "C" void kernel_launch(void* const* d_in, const int* in_sizes, int n_in,
                              void* d_out, int out_size, void* d_ws, size_t ws_size,
                              hipStream_t stream) {
    const float* y  = (const float*)d_in[0];
    const float* Wq = (const float*)d_in[1];
    const float* Wk = (const float*)d_in[2];
    const float* Wv = (const float*)d_in[3];
    float* outp = (float*)d_out;

    const int rows = in_sizes[0] / NINP;       // B*T = 16384
    const int nb = rows / TLEN;                // batches = 4
    const int rbn = rows / 64;                 // 256 row-blocks

    ushort* WT  = (ushort*)d_ws;               // 3*16384 bf16 = 96 KB
    ushort* Qh  = WT + 3 * 16384;              // rows*64 bf16 = 2 MB
    ushort* Kh  = Qh + (size_t)rows * DD;
    ushort* VhT = Kh + (size_t)rows * DD;      // [b][d][t]

    prep_wt<<<3, 256, 0, stream>>>(Wq, Wk, Wv, WT);
    qkv_kernel<<<3 * rbn, 256, 0, stream>>>(y, WT, Qh, Kh, VhT, rbn);
    attn_kernel<<<nb * 128, 512, 0, stream>>>(Qh, Kh, VhT, outp);
}